// Round 10
// baseline (886.151 us; speedup 1.0000x reference)
//
#include <hip/hip_runtime.h>
#include <hip/hip_bf16.h>

// Problem constants (static per reference)
#define NTOK 16384   // B*T
#define HD   512     // H
#define ED   8       // E experts
#define FD   2048    // F
#define CAP  5120    // capacity per expert
#define NA   32768   // NTOK * K(=2)

typedef __bf16 bf16x8 __attribute__((ext_vector_type(8)));
typedef float  f32x4  __attribute__((ext_vector_type(4)));

// Workspace layout (bytes). Total ~249 MB.
static constexpr size_t OFF_EIDX = 0;                                  // int[NA]
static constexpr size_t OFF_WGT  = 131072;                             // float[NA]
static constexpr size_t OFF_STOK = 262144;                             // int[ED*CAP]
static constexpr size_t OFF_ASLOT= 425984;                             // int[NA]
static constexpr size_t OFF_ECNT = 557056;                             // int[ED]
static constexpr size_t OFF_W2T  = 1u << 20;                           // bf16[ED][HD][FD]
static constexpr size_t OFF_H    = OFF_W2T + (size_t)ED*HD*FD*2;       // bf16[ED][CAP][FD]
static constexpr size_t OFF_W1T  = OFF_H   + (size_t)ED*CAP*FD*2;      // bf16[ED][FD][HD]
static constexpr size_t OFF_XBF  = OFF_W1T + (size_t)ED*FD*HD*2;       // bf16[NTOK][HD]
static constexpr size_t OFF_EOUT = OFF_XBF + (size_t)NTOK*HD*2;        // fp16[ED][CAP][HD]

__device__ __forceinline__ unsigned short f2bf(float f) {
    __bf16 b = (__bf16)f;
    return __builtin_bit_cast(unsigned short, b);
}
__device__ __forceinline__ unsigned short f2h(float f) {
    _Float16 h = (_Float16)f;
    return __builtin_bit_cast(unsigned short, h);
}
__device__ __forceinline__ float h2f(unsigned short u) {
    return (float)__builtin_bit_cast(_Float16, u);
}

// gelu(tanh approx) == v * sigmoid(2*0.79788456*(v + 0.044715 v^3))
// rcp (~1ulp) instead of exact div: invisible after bf16 rounding (R2).
__device__ __forceinline__ float gelu_fast(float v) {
    const float t = v * v;
    const float u = v * fmaf(t, 0.0713548214f, 1.5957691216f);
    const float e = __expf(-u);
    return v * __builtin_amdgcn_rcpf(1.f + e);
}

// ---------------------------------------------------------------------------
// Fused weight transposes: z<ED -> w1 [HD][FD] -> w1t [FD][HD];
//                          z>=ED -> w2 [FD][HD] -> w2t [HD][FD].
// (One launch instead of two: fewer dispatch gaps.)
// ---------------------------------------------------------------------------
__global__ __launch_bounds__(256) void transpose_cast_kernel(
    const float* __restrict__ w1, unsigned short* __restrict__ w1t,
    const float* __restrict__ w2, unsigned short* __restrict__ w2t)
{
    __shared__ unsigned short tile[32][33];
    const int z = blockIdx.z;
    const bool is1 = z < ED;
    const int e = is1 ? z : z - ED;
    const int R = is1 ? HD : FD;
    const int C = is1 ? FD : HD;
    if (blockIdx.x * 32 >= C || blockIdx.y * 32 >= R) return;
    const float* in = (is1 ? w1 : w2) + (size_t)e * HD * FD;
    unsigned short* out = (is1 ? w1t : w2t) + (size_t)e * HD * FD;
    const int r0 = blockIdx.y * 32, c0 = blockIdx.x * 32;
    const int tr = threadIdx.x >> 3, tc = (threadIdx.x & 7) * 4;
    const float4 v = *(const float4*)(in + (size_t)(r0 + tr) * C + c0 + tc);
    tile[tr][tc + 0] = f2bf(v.x);
    tile[tr][tc + 1] = f2bf(v.y);
    tile[tr][tc + 2] = f2bf(v.z);
    tile[tr][tc + 3] = f2bf(v.w);
    __syncthreads();
    ushort4 o;
    o.x = tile[tc + 0][tr]; o.y = tile[tc + 1][tr];
    o.z = tile[tc + 2][tr]; o.w = tile[tc + 3][tr];
    *(ushort4*)(out + (size_t)(c0 + tr) * R + r0 + tc) = o;
}

// ---------------------------------------------------------------------------
// Router (+ fused x->bf16 cast)
// ---------------------------------------------------------------------------
__global__ __launch_bounds__(256) void router_kernel(
    const float* __restrict__ x, const float* __restrict__ rw,
    int* __restrict__ eidx, float* __restrict__ wgt,
    unsigned short* __restrict__ xbf)
{
    __shared__ float rws[HD * ED];
    const int tid = threadIdx.x;
    for (int i = tid * 4; i < HD * ED; i += 256 * 4)
        *(float4*)(rws + i) = *(const float4*)(rw + i);
    __syncthreads();

    const int wid = tid >> 6, lane = tid & 63;
    const int t = blockIdx.x * 4 + wid;
    const float* xr = x + (size_t)t * HD;

    float acc[ED];
#pragma unroll
    for (int e = 0; e < ED; e++) acc[e] = 0.f;

    float4 xv0 = *(const float4*)(xr + lane * 8);
    float4 xv1 = *(const float4*)(xr + lane * 8 + 4);
    float xv[8] = {xv0.x, xv0.y, xv0.z, xv0.w, xv1.x, xv1.y, xv1.z, xv1.w};

    union { unsigned short us[8]; uint4 v; } pk;
#pragma unroll
    for (int j = 0; j < 8; j++) pk.us[j] = f2bf(xv[j]);
    *(uint4*)(xbf + (size_t)t * HD + lane * 8) = pk.v;

#pragma unroll
    for (int j = 0; j < 8; j++) {
        const int h = lane * 8 + j;
#pragma unroll
        for (int e = 0; e < ED; e++) acc[e] += xv[j] * rws[h * ED + e];
    }
#pragma unroll
    for (int off = 32; off >= 1; off >>= 1) {
#pragma unroll
        for (int e = 0; e < ED; e++) acc[e] += __shfl_down(acc[e], off);
    }
    if (lane == 0) {
        int e0 = 0; float l0 = acc[0];
        for (int e = 1; e < ED; e++) if (acc[e] > l0) { l0 = acc[e]; e0 = e; }
        int e1 = 0; float l1 = -1e30f;
        for (int e = 0; e < ED; e++) {
            if (e == e0) continue;
            if (acc[e] > l1) { l1 = acc[e]; e1 = e; }
        }
        const float ex = expf(l1 - l0);
        const float inv = 1.f / (1.f + ex);
        eidx[t * 2 + 0] = e0;  eidx[t * 2 + 1] = e1;
        wgt [t * 2 + 0] = inv; wgt [t * 2 + 1] = ex * inv;
    }
}

// ---------------------------------------------------------------------------
// Deterministic slot assignment (stable-sort-by-expert), parallel 3-pass scan.
// ---------------------------------------------------------------------------
__global__ __launch_bounds__(1024) void scan_kernel(
    const int* __restrict__ eidx,
    int* __restrict__ stok, int* __restrict__ aslot, int* __restrict__ ecnt)
{
    __shared__ int wcnt[32][16][ED];
    __shared__ int woff[32][16][ED];
    const int tid = threadIdx.x;
    const int lane = tid & 63, wid = tid >> 6;
    const unsigned long long below = (1ull << lane) - 1ull;

    for (int i = tid; i < ED * CAP; i += 1024) stok[i] = -1;

    for (int c = 0; c < NA / 1024; c++) {
        const int e = eidx[c * 1024 + tid];
#pragma unroll
        for (int ee = 0; ee < ED; ee++) {
            unsigned long long m = __ballot(e == ee);
            if (lane == 0) wcnt[c][wid][ee] = __popcll(m);
        }
    }
    __syncthreads();

    if (wid < ED) {
        const int e = wid;
        int carry = 0;
#pragma unroll
        for (int r = 0; r < 8; r++) {
            const int idx = r * 64 + lane;
            const int v = wcnt[idx >> 4][idx & 15][e];
            int s = v;
#pragma unroll
            for (int off = 1; off < 64; off <<= 1) {
                int u = __shfl_up(s, off);
                if (lane >= off) s += u;
            }
            woff[idx >> 4][idx & 15][e] = carry + s - v;
            carry += __shfl(s, 63);
        }
        if (lane == 0) ecnt[e] = carry < CAP ? carry : CAP;
    }
    __syncthreads();

    for (int c = 0; c < NA / 1024; c++) {
        const int a = c * 1024 + tid;
        const int e = eidx[a];
        int myrank = 0;
#pragma unroll
        for (int ee = 0; ee < ED; ee++) {
            unsigned long long m = __ballot(e == ee);
            if (ee == e) myrank = __popcll(m & below);
        }
        const int slot = woff[c][wid][e] + myrank;
        if (slot < CAP) {
            stok[e * CAP + slot] = a >> 1;
            aslot[a] = slot;
        } else {
            aslot[a] = -1;
        }
    }
}

// ---------------------------------------------------------------------------
// MFMA GEMM, R10: 256x128 block tile, 4 waves (2m x 2n), wave tile 128x64.
// R9 post-mortem: six schedule variants all pin MfmaUtil ~21% because the
// 64x64 wave tile fixes LDS traffic at 21.3 FLOP/byte (48KB per 1.05 MFLOP
// per K-step) — the schedule was never the binding constraint. 128x64 wave
// tiles give 29.1 FLOP/byte (72KB per 2.1 MFLOP): ds-read 12KB/wave instead
// of 8KB for 2x the FLOP. Everything else is R9's verified pipeline:
// reg-staged (global->VGPR->swizzled ds_write; per-register vmcnt tracking
// keeps loads in flight across barriers), ONE lgkm-only barrier per BK=32
// step, XOR swizzle (0 conflicts measured), swapped-operand MFMA epilogue.
// LDS 48KB (A 2x16 + B 2x8) -> 3 blocks/CU by LDS, ~2 by VGPR (~240 regs:
// acc 128 + frags 48 + staging 24). NOTE (R1): no min-waves floor.
// G1=true : hout = gelu(gather(x) @ B + bias)  [bf16]
// G1=false: hout = A @ B + bias                [fp16]
// ---------------------------------------------------------------------------
template<int KD, int ND, int NT, bool G1>
__global__ __launch_bounds__(256) void gemm_mfma(
    const unsigned short* __restrict__ Abase,
    const unsigned short* __restrict__ Bt,
    const float* __restrict__ bias,
    const int* __restrict__ stok,
    const int* __restrict__ ecnt,
    unsigned short* __restrict__ hout)
{
    constexpr int ABUF = 256 * 32;            // 8192 elems = 16 KB per buf
    constexpr int BBUF = 128 * 32;            // 4096 elems =  8 KB per buf
    __shared__ __align__(16) unsigned short As[2 * ABUF];
    __shared__ __align__(16) unsigned short Bs[2 * BBUF];

    const int tid = threadIdx.x;
    const int e  = blockIdx.x & 7;            // expert == XCD (id%8 round-robin)
    const int g  = blockIdx.x >> 3;
    const int n0 = (g % NT) * 128;            // n fastest: reuse gathered A in L2
    const int m0 = (g / NT) * 256;

    if (m0 >= ecnt[e]) return;                // padding tile: skip

    const int lane = tid & 63;
    const int wid  = tid >> 6;

    // Staging: q = 16B chunk, r = base row. A rows r+{0,64,128,192} (4 loads),
    // B rows r+{0,64} (2 loads). All share one XOR class ((r+i*64)>>1 & 3 is
    // invariant in i) -> one swizzled chunk cSw for all 6 ds_writes.
    const int q = tid & 3;
    const int r = tid >> 2;                   // 0..63

    unsigned int aoff[4], boff[2];
#pragma unroll
    for (int i = 0; i < 4; i++) {
        unsigned int arow;
        if constexpr (G1) {
            const int t = stok[e * CAP + m0 + r + i * 64];
            arow = (unsigned int)(t >= 0 ? t : 0);   // dropped -> row 0
        } else {
            arow = (unsigned int)(e * CAP + m0 + r + i * 64);
        }
        aoff[i] = arow * KD + q * 8;
    }
#pragma unroll
    for (int i = 0; i < 2; i++)
        boff[i] = (unsigned int)((e * ND + n0 + r + i * 64) * KD) + q * 8;

    const int cSw = q ^ ((r >> 1) & 3);
    int oWa[4], oWb[2];
#pragma unroll
    for (int i = 0; i < 4; i++) oWa[i] = (r + i * 64) * 32 + cSw * 8;
#pragma unroll
    for (int i = 0; i < 2; i++) oWb[i] = (r + i * 64) * 32 + cSw * 8;

    // Fragment read bases (R9-verified 0-conflict pattern).
    const int wm = wid >> 1, wn = wid & 1;    // wave tile: rows wm*128, cols wn*64
    const int l15  = lane & 15;
    const int quad = lane >> 4;
    const int xq   = quad ^ ((l15 >> 1) & 3);
    const int fA   = (wm * 128 + l15) * 32 + xq * 8;
    const int fB   = (wn * 64 + l15) * 32 + xq * 8;

    f32x4 acc[8][4];
#pragma unroll
    for (int i = 0; i < 8; i++)
#pragma unroll
        for (int j = 0; j < 4; j++) acc[i][j] = (f32x4)0.f;

// Swapped-operand MFMA: D = bfv x af -> col(lane&15) indexes m, row indexes n.
#define COMPUTE(PBUF)                                                          \
    {                                                                          \
        const unsigned short* Ab = As + (PBUF) * ABUF;                         \
        const unsigned short* Bb = Bs + (PBUF) * BBUF;                         \
        bf16x8 af[8], bfv[4];                                                  \
        _Pragma("unroll")                                                      \
        for (int i = 0; i < 8; i++) af[i]  = *(const bf16x8*)(Ab + fA + i * 512); \
        _Pragma("unroll")                                                      \
        for (int j = 0; j < 4; j++) bfv[j] = *(const bf16x8*)(Bb + fB + j * 512); \
        _Pragma("unroll")                                                      \
        for (int i = 0; i < 8; i++)                                            \
            _Pragma("unroll")                                                  \
            for (int j = 0; j < 4; j++)                                        \
                acc[i][j] = __builtin_amdgcn_mfma_f32_16x16x32_bf16(           \
                    bfv[j], af[i], acc[i][j], 0, 0, 0);                        \
    }

#define LOADT(KC)                                                              \
    {                                                                          \
        _Pragma("unroll")                                                      \
        for (int i = 0; i < 4; i++) ra[i] = *(const float4*)(Abase + aoff[i] + (KC)); \
        _Pragma("unroll")                                                      \
        for (int i = 0; i < 2; i++) rb[i] = *(const float4*)(Bt + boff[i] + (KC)); \
    }

#define WRITET(WB)                                                             \
    {                                                                          \
        _Pragma("unroll")                                                      \
        for (int i = 0; i < 4; i++) *(float4*)(&As[(WB) * ABUF + oWa[i]]) = ra[i]; \
        _Pragma("unroll")                                                      \
        for (int i = 0; i < 2; i++) *(float4*)(&Bs[(WB) * BBUF + oWb[i]]) = rb[i]; \
    }

// lgkm-only barrier: ds traffic ordered; in-flight global->reg loads survive.
#define LBAR asm volatile("s_waitcnt lgkmcnt(0)\n\ts_barrier" ::: "memory")

    float4 ra[4], rb[2];
    // Prologue: tile 0 -> regs -> buf0; tile 1 -> regs (in flight).
    LOADT(0);
    WRITET(0);
    LOADT(32);
    LBAR;

    int rbuf = 0;
    for (int kc = 0; kc < KD; kc += 32) {
        if (kc + 32 < KD) {
            WRITET(rbuf ^ 1);                 // vmcnt waits land here, precise
            if (kc + 64 < KD) LOADT(kc + 64);
        }
        COMPUTE(rbuf);
        LBAR;
        rbuf ^= 1;
    }
#undef COMPUTE
#undef LOADT
#undef WRITET
#undef LBAR

    // Epilogue (transposed D): m = wm*128 + i*16 + l15, n = wn*64 + j*16 +
    // quad*4 + g2 -> one ushort4 store per (i,j).
    float4 b4[4];
#pragma unroll
    for (int j = 0; j < 4; j++)
        b4[j] = *(const float4*)(bias + (size_t)e * ND + n0 + wn * 64 + j * 16 + quad * 4);
#pragma unroll
    for (int i = 0; i < 8; i++) {
        unsigned short* hrow = hout
            + ((size_t)e * CAP + m0 + wm * 128 + i * 16 + l15) * ND
            + n0 + wn * 64 + quad * 4;
#pragma unroll
        for (int j = 0; j < 4; j++) {
            const float v0 = acc[i][j][0] + b4[j].x;
            const float v1 = acc[i][j][1] + b4[j].y;
            const float v2 = acc[i][j][2] + b4[j].z;
            const float v3 = acc[i][j][3] + b4[j].w;
            ushort4 o;
            if constexpr (G1) {
                o.x = f2bf(gelu_fast(v0)); o.y = f2bf(gelu_fast(v1));
                o.z = f2bf(gelu_fast(v2)); o.w = f2bf(gelu_fast(v3));
            } else {
                o.x = f2h(v0); o.y = f2h(v1); o.z = f2h(v2); o.w = f2h(v3);
            }
            *(ushort4*)(hrow + j * 16) = o;
        }
    }
}

// ---------------------------------------------------------------------------
// Combine: out[t] = sum_k wgt[t,k] * eout[eidx[t,k], aslot[t,k]]
// ---------------------------------------------------------------------------
__global__ __launch_bounds__(256) void combine_kernel(
    const unsigned short* __restrict__ eout,
    const int* __restrict__ eidx, const int* __restrict__ aslot,
    const float* __restrict__ wgt, float* __restrict__ out)
{
    const int tid = threadIdx.x;
    const int t  = blockIdx.x * 2 + (tid >> 7);
    const int h0 = (tid & 127) * 4;
    float r0 = 0.f, r1 = 0.f, r2 = 0.f, r3 = 0.f;
#pragma unroll
    for (int k = 0; k < 2; k++) {
        const int a = t * 2 + k;
        const int s = aslot[a];
        if (s >= 0) {
            const float w = wgt[a];
            const int e = eidx[a];
            const ushort4 v = *(const ushort4*)(eout + ((size_t)e * CAP + s) * HD + h0);
            r0 += w * h2f(v.x); r1 += w * h2f(v.y);
            r2 += w * h2f(v.z); r3 += w * h2f(v.w);
        }
    }
    float4 o; o.x = r0; o.y = r1; o.z = r2; o.w = r3;
    *(float4*)(out + (size_t)t * HD + h0) = o;
}

extern "C" void kernel_launch(void* const* d_in, const int* in_sizes, int n_in,
                              void* d_out, int out_size, void* d_ws, size_t ws_size,
                              hipStream_t stream)
{
    const float* x  = (const float*)d_in[0];
    const float* rw = (const float*)d_in[1];
    const float* w1 = (const float*)d_in[2];
    const float* b1 = (const float*)d_in[3];
    const float* w2 = (const float*)d_in[4];
    const float* b2 = (const float*)d_in[5];
    float* out = (float*)d_out;

    char* ws = (char*)d_ws;
    int*   eidx  = (int*)  (ws + OFF_EIDX);
    float* wgt   = (float*)(ws + OFF_WGT);
    int*   stok  = (int*)  (ws + OFF_STOK);
    int*   aslot = (int*)  (ws + OFF_ASLOT);
    int*   ecnt  = (int*)  (ws + OFF_ECNT);
    unsigned short* w2t  = (unsigned short*)(ws + OFF_W2T);
    unsigned short* hbuf = (unsigned short*)(ws + OFF_H);
    unsigned short* w1t  = (unsigned short*)(ws + OFF_W1T);
    unsigned short* xbf  = (unsigned short*)(ws + OFF_XBF);
    unsigned short* eout = (unsigned short*)(ws + OFF_EOUT);

    // Both weight transposes in one launch (z<8: w1, z>=8: w2; surplus blocks
    // exit immediately).
    transpose_cast_kernel<<<dim3(FD / 32, FD / 32, 2 * ED), 256, 0, stream>>>(
        w1, w1t, w2, w2t);
    router_kernel<<<NTOK / 4, 256, 0, stream>>>(x, rw, eidx, wgt, xbf);
    scan_kernel<<<1, 1024, 0, stream>>>(eidx, stok, aslot, ecnt);

    // GEMM1: h = gelu(gather(x) @ w1 + b1)  [bf16], 256x128 tiles
    gemm_mfma<HD, FD, FD/128, true>
        <<<8 * (FD/128) * (CAP/256), 256, 0, stream>>>(
        xbf, w1t, b1, stok, ecnt, hbuf);

    // GEMM2: eout = h @ w2 + b2  [fp16, per-slot], 256x128 tiles
    gemm_mfma<FD, HD, HD/128, false>
        <<<8 * (HD/128) * (CAP/256), 256, 0, stream>>>(
        hbuf, w2t, b2, nullptr, ecnt, eout);

    combine_kernel<<<NTOK / 2, 256, 0, stream>>>(eout, eidx, aslot, wgt, out);
}